// Round 2
// baseline (216.486 us; speedup 1.0000x reference)
//
#include <hip/hip_runtime.h>
#include <math.h>

#define BB   64
#define SS   576
#define DD   768
#define KTOP 63
#define KEEP 64
#define HH   128
#define NROW (BB*KEEP + BB)   // 4160 rows through the autoencoder

// ---------------- K1: cls attention scores (f64 accumulate for exact ranking) ---
__global__ __launch_bounds__(256) void k_scores(const float* __restrict__ cls,
                                                const float* __restrict__ fm,
                                                float* __restrict__ scores)
{
  int gw = (blockIdx.x * blockDim.x + threadIdx.x) >> 6;   // one wave per (b,s)
  int lane = threadIdx.x & 63;
  if (gw >= BB * SS) return;
  int b = gw / SS, s = gw - b * SS;
  const float4* frow = (const float4*)(fm + ((size_t)b * SS + s) * DD);
  const float4* crow = (const float4*)(cls + (size_t)b * DD);
  double acc = 0.0;
#pragma unroll
  for (int j = 0; j < 3; ++j) {
    float4 f = frow[lane + 64 * j];
    float4 c = crow[lane + 64 * j];
    acc += (double)f.x * c.x + (double)f.y * c.y + (double)f.z * c.z + (double)f.w * c.w;
  }
#pragma unroll
  for (int off = 32; off > 0; off >>= 1) acc += __shfl_down(acc, off, 64);
  if (lane == 0) scores[(size_t)b * SS + s] = (float)acc;
}

// ---------------- K2a: top-63 selection, sorted desc, ties -> lowest index -----
__global__ __launch_bounds__(64) void k_topk(const float* __restrict__ scores,
                                             int* __restrict__ idxout)
{
  int b = blockIdx.x, lane = threadIdx.x;
  unsigned long long key[9];
#pragma unroll
  for (int j = 0; j < 9; ++j) {
    int idx = lane + 64 * j;                       // covers 0..575
    unsigned int u = __float_as_uint(scores[(size_t)b * SS + idx]);
    u = (u & 0x80000000u) ? ~u : (u | 0x80000000u);   // order-preserving map
    key[j] = ((unsigned long long)u << 32) |
             (unsigned long long)(0xFFFFFFFFu - (unsigned)idx);  // ties: lower idx wins
  }
  for (int k = 0; k < KTOP; ++k) {
    unsigned long long best = key[0];
#pragma unroll
    for (int j = 1; j < 9; ++j) best = key[j] > best ? key[j] : best;
#pragma unroll
    for (int off = 32; off > 0; off >>= 1) {
      unsigned long long o = __shfl_xor(best, off, 64);
      best = o > best ? o : best;
    }
    int idx = (int)(0xFFFFFFFFu - (unsigned int)best);
    if (lane == 0) idxout[b * KEEP + k] = idx;
    if ((idx & 63) == lane) {                       // remove winner
      int wj = idx >> 6;
#pragma unroll
      for (int j = 0; j < 9; ++j) if (j == wj) key[j] = 0ull;
    }
  }
}

// ---------------- K2b: masked softmax weights + pooled extra token -------------
__global__ __launch_bounds__(256) void k_extra(const float* __restrict__ scores,
                                               const int* __restrict__ idxin,
                                               const float* __restrict__ fm,
                                               float* __restrict__ extra)
{
  __shared__ float w[SS];
  __shared__ unsigned char flag[SS];
  __shared__ float redm[4], redz[4];
  int b = blockIdx.x, tid = threadIdx.x;
  int d = blockIdx.y * 256 + tid;                   // grid.y = 3 -> d in 0..767
  for (int i = tid; i < SS; i += 256) { flag[i] = 0; w[i] = scores[(size_t)b * SS + i]; }
  __syncthreads();
  if (tid < KTOP) flag[idxin[b * KEEP + tid]] = 1;
  __syncthreads();
  // max over unselected (selected logits are score-10000 -> never the max)
  float m = -1e30f;
  for (int i = tid; i < SS; i += 256) if (!flag[i]) m = fmaxf(m, w[i]);
#pragma unroll
  for (int off = 32; off; off >>= 1) m = fmaxf(m, __shfl_xor(m, off, 64));
  if ((tid & 63) == 0) redm[tid >> 6] = m;
  __syncthreads();
  m = fmaxf(fmaxf(redm[0], redm[1]), fmaxf(redm[2], redm[3]));
  // e_s (selected -> exactly 0, matching f32 exp(-1e4) underflow in the reference)
  float zp = 0.f;
  for (int i = tid; i < SS; i += 256) {
    float e = flag[i] ? 0.f : expf(w[i] - m);
    w[i] = e; zp += e;
  }
#pragma unroll
  for (int off = 32; off; off >>= 1) zp += __shfl_xor(zp, off, 64);
  if ((tid & 63) == 0) redz[tid >> 6] = zp;
  __syncthreads();
  float Z = redz[0] + redz[1] + redz[2] + redz[3];
  // weighted sum over tokens for this dim slice (fm is L3-resident after K1)
  float acc = 0.f;
  const float* fcol = fm + (size_t)b * SS * DD + d;
#pragma unroll 8
  for (int s = 0; s < SS; ++s) acc += w[s] * fcol[(size_t)s * DD];
  extra[(size_t)b * DD + d] = acc / Z;
}

// ---------------- K3: gather rows + H = tanh(X @ W1 + b1) ----------------------
// One wave owns 2 rows; lane l: row = r0 + (l>>5), cols = (l&31)*4 .. +3.
// X rows staged in LDS (broadcast reads), W1 streamed from global (L2-hot).
// No barriers in the K-loop; 8 rows/block, 520 blocks -> 2+ blocks/CU.
__global__ __launch_bounds__(256, 2) void k_ae1(const float* __restrict__ fm,
                                                const float* __restrict__ cls,
                                                const float* __restrict__ extra,
                                                const int* __restrict__ idxin,
                                                const float* __restrict__ W1,
                                                const float* __restrict__ b1,
                                                float* __restrict__ H)
{
  __shared__ float Xl[8][DD];          // 24 KB
  __shared__ const float* rowptr[8];
  int tid = threadIdx.x;
  int rowbase = blockIdx.x * 8;
  if (tid < 8) {
    int row = rowbase + tid;
    const float* p;
    if (row < BB * KEEP) {
      int b = row >> 6, k = row & 63;
      p = (k < KTOP) ? fm + ((size_t)b * SS + idxin[b * KEEP + k]) * DD
                     : extra + (size_t)b * DD;
    } else {
      p = cls + (size_t)(row - BB * KEEP) * DD;
    }
    rowptr[tid] = p;
  }
  __syncthreads();
  for (int e = tid; e < 8 * (DD / 4); e += 256) {   // float4 gather into LDS
    int r = e / (DD / 4), k4 = e - r * (DD / 4);
    ((float4*)Xl[r])[k4] = ((const float4*)rowptr[r])[k4];
  }
  __syncthreads();

  int wave = tid >> 6, lane = tid & 63;
  int rloc = wave * 2 + (lane >> 5);                // local row 0..7
  int c4 = lane & 31;                               // float4 column index (0..31)
  const float4* __restrict__ W1v = (const float4*)W1;   // [768][32] float4
  const float4* __restrict__ Xv  = (const float4*)Xl[rloc];
  float4 acc = make_float4(0.f, 0.f, 0.f, 0.f);

#pragma unroll 4
  for (int q = 0; q < DD / 4; ++q) {                // 4 K values per iter
    float4 x4 = Xv[q];                              // LDS broadcast (b128)
#pragma unroll
    for (int kk = 0; kk < 4; ++kk) {
      float xk = (kk == 0) ? x4.x : (kk == 1) ? x4.y : (kk == 2) ? x4.z : x4.w;
      float4 wv = W1v[(size_t)(4 * q + kk) * 32 + c4];
      acc.x = fmaf(xk, wv.x, acc.x);
      acc.y = fmaf(xk, wv.y, acc.y);
      acc.z = fmaf(xk, wv.z, acc.z);
      acc.w = fmaf(xk, wv.w, acc.w);
    }
  }
  float4 bv = ((const float4*)b1)[c4];
  float4 h;
  h.x = tanhf(acc.x + bv.x);
  h.y = tanhf(acc.y + bv.y);
  h.z = tanhf(acc.z + bv.z);
  h.w = tanhf(acc.w + bv.w);
  ((float4*)(H + (size_t)(rowbase + rloc) * HH))[c4] = h;
}

// ---------------- K4: out = H @ W2 + b2 ----------------------------------------
// Same structure: wave owns 2 rows, lane covers 24 cols (6 x float4 strided 128).
__global__ __launch_bounds__(256, 2) void k_ae2(const float* __restrict__ H,
                                                const float* __restrict__ W2,
                                                const float* __restrict__ b2,
                                                float* __restrict__ out)
{
  __shared__ float Hl[8][HH];          // 4 KB
  int tid = threadIdx.x;
  int rowbase = blockIdx.x * 8;
  {
    int r = tid >> 5, k4 = tid & 31;   // 256 threads = 8 rows x 32 float4
    ((float4*)Hl[r])[k4] = ((const float4*)(H + (size_t)(rowbase + r) * HH))[k4];
  }
  __syncthreads();

  int wave = tid >> 6, lane = tid & 63;
  int rloc = wave * 2 + (lane >> 5);
  int c4 = lane & 31;
  const float4* __restrict__ W2v = (const float4*)W2;   // [128][192] float4
  const float4* __restrict__ Hv  = (const float4*)Hl[rloc];
  float4 acc[6];
#pragma unroll
  for (int j = 0; j < 6; ++j) acc[j] = make_float4(0.f, 0.f, 0.f, 0.f);

#pragma unroll 2
  for (int q = 0; q < HH / 4; ++q) {                // 4 K values per iter
    float4 h4 = Hv[q];                              // LDS broadcast
#pragma unroll
    for (int kk = 0; kk < 4; ++kk) {
      float hk = (kk == 0) ? h4.x : (kk == 1) ? h4.y : (kk == 2) ? h4.z : h4.w;
#pragma unroll
      for (int j = 0; j < 6; ++j) {
        float4 wv = W2v[(size_t)(4 * q + kk) * 192 + j * 32 + c4];
        acc[j].x = fmaf(hk, wv.x, acc[j].x);
        acc[j].y = fmaf(hk, wv.y, acc[j].y);
        acc[j].z = fmaf(hk, wv.z, acc[j].z);
        acc[j].w = fmaf(hk, wv.w, acc[j].w);
      }
    }
  }
  float4* orow = (float4*)(out + (size_t)(rowbase + rloc) * DD);
#pragma unroll
  for (int j = 0; j < 6; ++j) {
    float4 bv = ((const float4*)b2)[j * 32 + c4];
    float4 y;
    y.x = acc[j].x + bv.x; y.y = acc[j].y + bv.y;
    y.z = acc[j].z + bv.z; y.w = acc[j].w + bv.w;
    orow[j * 32 + c4] = y;
  }
}

extern "C" void kernel_launch(void* const* d_in, const int* in_sizes, int n_in,
                              void* d_out, int out_size, void* d_ws, size_t ws_size,
                              hipStream_t stream)
{
  const float* cls = (const float*)d_in[0];
  const float* fm  = (const float*)d_in[1];
  const float* W1  = (const float*)d_in[2];
  const float* b1  = (const float*)d_in[3];
  const float* W2  = (const float*)d_in[4];
  const float* b2  = (const float*)d_in[5];
  float* out = (float*)d_out;

  char* ws = (char*)d_ws;
  float* scores = (float*)ws;                                  // 64*576*4   = 147456 B
  int*   idx    = (int*)(ws + 147456);                         // 64*64*4    =  16384 B
  float* extra  = (float*)(ws + 147456 + 16384);               // 64*768*4   = 196608 B
  float* H      = (float*)(ws + 147456 + 16384 + 196608);      // 4160*128*4 = 2129920 B

  hipLaunchKernelGGL(k_scores, dim3((BB * SS) / 4), dim3(256), 0, stream, cls, fm, scores);
  hipLaunchKernelGGL(k_topk,   dim3(BB),            dim3(64),  0, stream, scores, idx);
  hipLaunchKernelGGL(k_extra,  dim3(BB, 3),         dim3(256), 0, stream, scores, idx, fm, extra);
  hipLaunchKernelGGL(k_ae1,    dim3(NROW / 8),      dim3(256), 0, stream,
                     fm, cls, extra, idx, W1, b1, H);
  hipLaunchKernelGGL(k_ae2,    dim3(NROW / 8),      dim3(256), 0, stream, H, W2, b2, out);
}

// Round 3
// 214.905 us; speedup vs baseline: 1.0074x; 1.0074x over previous
//
#include <hip/hip_runtime.h>
#include <math.h>

#define BB   64
#define SS   576
#define DD   768
#define KTOP 63
#define KEEP 64
#define HH   128
#define NROW (BB*KEEP + BB)   // 4160 rows through the autoencoder

// ---------------- K1: cls attention scores (f64 accumulate for exact ranking) ---
__global__ __launch_bounds__(256) void k_scores(const float* __restrict__ cls,
                                                const float* __restrict__ fm,
                                                float* __restrict__ scores)
{
  int gw = (blockIdx.x * blockDim.x + threadIdx.x) >> 6;   // one wave per (b,s)
  int lane = threadIdx.x & 63;
  if (gw >= BB * SS) return;
  int b = gw / SS, s = gw - b * SS;
  const float4* frow = (const float4*)(fm + ((size_t)b * SS + s) * DD);
  const float4* crow = (const float4*)(cls + (size_t)b * DD);
  double acc = 0.0;
#pragma unroll
  for (int j = 0; j < 3; ++j) {
    float4 f = frow[lane + 64 * j];
    float4 c = crow[lane + 64 * j];
    acc += (double)f.x * c.x + (double)f.y * c.y + (double)f.z * c.z + (double)f.w * c.w;
  }
#pragma unroll
  for (int off = 32; off > 0; off >>= 1) acc += __shfl_down(acc, off, 64);
  if (lane == 0) scores[(size_t)b * SS + s] = (float)acc;
}

// ---------------- K2a: top-63 selection, sorted desc, ties -> lowest index -----
__global__ __launch_bounds__(64) void k_topk(const float* __restrict__ scores,
                                             int* __restrict__ idxout)
{
  int b = blockIdx.x, lane = threadIdx.x;
  unsigned long long key[9];
#pragma unroll
  for (int j = 0; j < 9; ++j) {
    int idx = lane + 64 * j;                       // covers 0..575
    unsigned int u = __float_as_uint(scores[(size_t)b * SS + idx]);
    u = (u & 0x80000000u) ? ~u : (u | 0x80000000u);   // order-preserving map
    key[j] = ((unsigned long long)u << 32) |
             (unsigned long long)(0xFFFFFFFFu - (unsigned)idx);  // ties: lower idx wins
  }
  for (int k = 0; k < KTOP; ++k) {
    unsigned long long best = key[0];
#pragma unroll
    for (int j = 1; j < 9; ++j) best = key[j] > best ? key[j] : best;
#pragma unroll
    for (int off = 32; off > 0; off >>= 1) {
      unsigned long long o = __shfl_xor(best, off, 64);
      best = o > best ? o : best;
    }
    int idx = (int)(0xFFFFFFFFu - (unsigned int)best);
    if (lane == 0) idxout[b * KEEP + k] = idx;
    if ((idx & 63) == lane) {                       // remove winner
      int wj = idx >> 6;
#pragma unroll
      for (int j = 0; j < 9; ++j) if (j == wj) key[j] = 0ull;
    }
  }
}

// ---------------- K2b: masked softmax weights + pooled extra token -------------
__global__ __launch_bounds__(256) void k_extra(const float* __restrict__ scores,
                                               const int* __restrict__ idxin,
                                               const float* __restrict__ fm,
                                               float* __restrict__ extra)
{
  __shared__ float w[SS];
  __shared__ unsigned char flag[SS];
  __shared__ float redm[4], redz[4];
  int b = blockIdx.x, tid = threadIdx.x;
  int d = blockIdx.y * 256 + tid;                   // grid.y = 3 -> d in 0..767
  for (int i = tid; i < SS; i += 256) { flag[i] = 0; w[i] = scores[(size_t)b * SS + i]; }
  __syncthreads();
  if (tid < KTOP) flag[idxin[b * KEEP + tid]] = 1;
  __syncthreads();
  // max over unselected (selected logits are score-10000 -> never the max)
  float m = -1e30f;
  for (int i = tid; i < SS; i += 256) if (!flag[i]) m = fmaxf(m, w[i]);
#pragma unroll
  for (int off = 32; off; off >>= 1) m = fmaxf(m, __shfl_xor(m, off, 64));
  if ((tid & 63) == 0) redm[tid >> 6] = m;
  __syncthreads();
  m = fmaxf(fmaxf(redm[0], redm[1]), fmaxf(redm[2], redm[3]));
  // e_s (selected -> exactly 0, matching f32 exp(-1e4) underflow in the reference)
  float zp = 0.f;
  for (int i = tid; i < SS; i += 256) {
    float e = flag[i] ? 0.f : expf(w[i] - m);
    w[i] = e; zp += e;
  }
#pragma unroll
  for (int off = 32; off; off >>= 1) zp += __shfl_xor(zp, off, 64);
  if ((tid & 63) == 0) redz[tid >> 6] = zp;
  __syncthreads();
  float Z = redz[0] + redz[1] + redz[2] + redz[3];
  // weighted sum over tokens for this dim slice; 4 partial sums break the
  // fmaf dependency chain (576 = 4*144)
  float a0 = 0.f, a1 = 0.f, a2 = 0.f, a3 = 0.f;
  const float* fcol = fm + (size_t)b * SS * DD + d;
#pragma unroll 4
  for (int s = 0; s < SS; s += 4) {
    a0 = fmaf(w[s + 0], fcol[(size_t)(s + 0) * DD], a0);
    a1 = fmaf(w[s + 1], fcol[(size_t)(s + 1) * DD], a1);
    a2 = fmaf(w[s + 2], fcol[(size_t)(s + 2) * DD], a2);
    a3 = fmaf(w[s + 3], fcol[(size_t)(s + 3) * DD], a3);
  }
  extra[(size_t)b * DD + d] = ((a0 + a1) + (a2 + a3)) / Z;
}

// ---------------- row gather: source pointer for AE row (wave-uniform) ---------
__device__ __forceinline__ const float* row_src(int row, const float* fm,
                                                const float* cls, const float* extra,
                                                const int* idxin)
{
  if (row < BB * KEEP) {
    int b = row >> 6, k = row & 63;
    if (k < KTOP) return fm + ((size_t)b * SS + idxin[b * KEEP + k]) * DD;
    return extra + (size_t)b * DD;
  }
  return cls + (size_t)(row - BB * KEEP) * DD;
}

// ---------------- K3: H = tanh(X @ W1 + b1), W1 panel resident in VGPRs --------
// 2080 wave-tasks = 520 rowgroups(8 rows) x 4 col-blocks(32 cols).
// Lane = (col 0..31, K-half 0..1); per K-panel of 128 each lane holds 64 W
// values in registers (compile-time indices only). X loads: one float4 feeds
// 16 register-operand FMAs. No LDS, no barriers. K-halves combined by
// shfl_xor(32) at the end.
__global__ __launch_bounds__(256, 2) void k_ae1(const float* __restrict__ fm,
                                                const float* __restrict__ cls,
                                                const float* __restrict__ extra,
                                                const int* __restrict__ idxin,
                                                const float* __restrict__ W1,
                                                const float* __restrict__ b1,
                                                float* __restrict__ H)
{
  int task = blockIdx.x * 4 + (threadIdx.x >> 6);
  int lane = threadIdx.x & 63;
  int rowgrp = task >> 2;
  int cblk = task & 3;
  int c = cblk * 32 + (lane & 31);
  int kh = lane >> 5;
  int row0 = rowgrp * 8;

  const float* rp[8];
#pragma unroll
  for (int r = 0; r < 8; ++r) rp[r] = row_src(row0 + r, fm, cls, extra, idxin);

  float acc[8] = {0.f, 0.f, 0.f, 0.f, 0.f, 0.f, 0.f, 0.f};

  for (int p = 0; p < 6; ++p) {                     // 6 K-panels of 128
    int kbase = p * 128 + kh * 64;
    float w[64];
    const float* Wp = W1 + (size_t)kbase * HH + c;
#pragma unroll
    for (int k = 0; k < 64; ++k) w[k] = Wp[(size_t)k * HH];

#pragma unroll
    for (int g = 0; g < 2; ++g) {                   // 2 groups of 4 rows
      const float4* x0 = (const float4*)(rp[g * 4 + 0] + kbase);
      const float4* x1 = (const float4*)(rp[g * 4 + 1] + kbase);
      const float4* x2 = (const float4*)(rp[g * 4 + 2] + kbase);
      const float4* x3 = (const float4*)(rp[g * 4 + 3] + kbase);
#pragma unroll
      for (int q = 0; q < 16; ++q) {                // 64 K per lane-half
        float4 a = x0[q], b = x1[q], d = x2[q], e = x3[q];
        float wk;
        wk = w[4 * q + 0];
        acc[g * 4 + 0] = fmaf(a.x, wk, acc[g * 4 + 0]);
        acc[g * 4 + 1] = fmaf(b.x, wk, acc[g * 4 + 1]);
        acc[g * 4 + 2] = fmaf(d.x, wk, acc[g * 4 + 2]);
        acc[g * 4 + 3] = fmaf(e.x, wk, acc[g * 4 + 3]);
        wk = w[4 * q + 1];
        acc[g * 4 + 0] = fmaf(a.y, wk, acc[g * 4 + 0]);
        acc[g * 4 + 1] = fmaf(b.y, wk, acc[g * 4 + 1]);
        acc[g * 4 + 2] = fmaf(d.y, wk, acc[g * 4 + 2]);
        acc[g * 4 + 3] = fmaf(e.y, wk, acc[g * 4 + 3]);
        wk = w[4 * q + 2];
        acc[g * 4 + 0] = fmaf(a.z, wk, acc[g * 4 + 0]);
        acc[g * 4 + 1] = fmaf(b.z, wk, acc[g * 4 + 1]);
        acc[g * 4 + 2] = fmaf(d.z, wk, acc[g * 4 + 2]);
        acc[g * 4 + 3] = fmaf(e.z, wk, acc[g * 4 + 3]);
        wk = w[4 * q + 3];
        acc[g * 4 + 0] = fmaf(a.w, wk, acc[g * 4 + 0]);
        acc[g * 4 + 1] = fmaf(b.w, wk, acc[g * 4 + 1]);
        acc[g * 4 + 2] = fmaf(d.w, wk, acc[g * 4 + 2]);
        acc[g * 4 + 3] = fmaf(e.w, wk, acc[g * 4 + 3]);
      }
    }
  }
#pragma unroll
  for (int r = 0; r < 8; ++r) acc[r] += __shfl_xor(acc[r], 32);
  float bv = b1[c];
  if (lane < 32) {
#pragma unroll
    for (int r = 0; r < 8; ++r)
      H[(size_t)(row0 + r) * HH + c] = tanhf(acc[r] + bv);
  }
}

// ---------------- K4: out = H @ W2 + b2, W2 slice resident in VGPRs ------------
// 6240 wave-tasks = 260 rowgroups(16 rows) x 24 col-blocks(32 cols).
// Lane = (col, K-half); each lane holds 64 of the 128 K values of its column.
__global__ __launch_bounds__(256, 2) void k_ae2(const float* __restrict__ H,
                                                const float* __restrict__ W2,
                                                const float* __restrict__ b2,
                                                float* __restrict__ out)
{
  int task = blockIdx.x * 4 + (threadIdx.x >> 6);
  int lane = threadIdx.x & 63;
  int rowgrp = task / 24;
  int cblk = task - rowgrp * 24;
  int c = cblk * 32 + (lane & 31);
  int kh = lane >> 5;
  int row0 = rowgrp * 16;

  float w[64];
  const float* Wp = W2 + (size_t)(kh * 64) * DD + c;
#pragma unroll
  for (int k = 0; k < 64; ++k) w[k] = Wp[(size_t)k * DD];
  float bv = b2[c];

#pragma unroll
  for (int g = 0; g < 4; ++g) {                     // 4 groups of 4 rows
    float acc0 = 0.f, acc1 = 0.f, acc2 = 0.f, acc3 = 0.f;
    const float4* x0 = (const float4*)(H + (size_t)(row0 + g * 4 + 0) * HH + kh * 64);
    const float4* x1 = (const float4*)(H + (size_t)(row0 + g * 4 + 1) * HH + kh * 64);
    const float4* x2 = (const float4*)(H + (size_t)(row0 + g * 4 + 2) * HH + kh * 64);
    const float4* x3 = (const float4*)(H + (size_t)(row0 + g * 4 + 3) * HH + kh * 64);
#pragma unroll
    for (int q = 0; q < 16; ++q) {
      float4 a = x0[q], b = x1[q], d = x2[q], e = x3[q];
      float wk;
      wk = w[4 * q + 0];
      acc0 = fmaf(a.x, wk, acc0); acc1 = fmaf(b.x, wk, acc1);
      acc2 = fmaf(d.x, wk, acc2); acc3 = fmaf(e.x, wk, acc3);
      wk = w[4 * q + 1];
      acc0 = fmaf(a.y, wk, acc0); acc1 = fmaf(b.y, wk, acc1);
      acc2 = fmaf(d.y, wk, acc2); acc3 = fmaf(e.y, wk, acc3);
      wk = w[4 * q + 2];
      acc0 = fmaf(a.z, wk, acc0); acc1 = fmaf(b.z, wk, acc1);
      acc2 = fmaf(d.z, wk, acc2); acc3 = fmaf(e.z, wk, acc3);
      wk = w[4 * q + 3];
      acc0 = fmaf(a.w, wk, acc0); acc1 = fmaf(b.w, wk, acc1);
      acc2 = fmaf(d.w, wk, acc2); acc3 = fmaf(e.w, wk, acc3);
    }
    acc0 += __shfl_xor(acc0, 32);
    acc1 += __shfl_xor(acc1, 32);
    acc2 += __shfl_xor(acc2, 32);
    acc3 += __shfl_xor(acc3, 32);
    if (lane < 32) {
      out[(size_t)(row0 + g * 4 + 0) * DD + c] = acc0 + bv;
      out[(size_t)(row0 + g * 4 + 1) * DD + c] = acc1 + bv;
      out[(size_t)(row0 + g * 4 + 2) * DD + c] = acc2 + bv;
      out[(size_t)(row0 + g * 4 + 3) * DD + c] = acc3 + bv;
    }
  }
}

extern "C" void kernel_launch(void* const* d_in, const int* in_sizes, int n_in,
                              void* d_out, int out_size, void* d_ws, size_t ws_size,
                              hipStream_t stream)
{
  const float* cls = (const float*)d_in[0];
  const float* fm  = (const float*)d_in[1];
  const float* W1  = (const float*)d_in[2];
  const float* b1  = (const float*)d_in[3];
  const float* W2  = (const float*)d_in[4];
  const float* b2  = (const float*)d_in[5];
  float* out = (float*)d_out;

  char* ws = (char*)d_ws;
  float* scores = (float*)ws;                                  // 64*576*4   = 147456 B
  int*   idx    = (int*)(ws + 147456);                         // 64*64*4    =  16384 B
  float* extra  = (float*)(ws + 147456 + 16384);               // 64*768*4   = 196608 B
  float* H      = (float*)(ws + 147456 + 16384 + 196608);      // 4160*128*4 = 2129920 B

  hipLaunchKernelGGL(k_scores, dim3((BB * SS) / 4), dim3(256), 0, stream, cls, fm, scores);
  hipLaunchKernelGGL(k_topk,   dim3(BB),            dim3(64),  0, stream, scores, idx);
  hipLaunchKernelGGL(k_extra,  dim3(BB, 3),         dim3(256), 0, stream, scores, idx, fm, extra);
  hipLaunchKernelGGL(k_ae1,    dim3(520),           dim3(256), 0, stream,
                     fm, cls, extra, idx, W1, b1, H);
  hipLaunchKernelGGL(k_ae2,    dim3(1560),          dim3(256), 0, stream, H, W2, b2, out);
}

// Round 4
// 131.127 us; speedup vs baseline: 1.6510x; 1.6389x over previous
//
#include <hip/hip_runtime.h>
#include <math.h>

#define BB   64
#define SS   576
#define DD   768
#define KTOP 63
#define KEEP 64
#define HH   128
#define NROW (BB*KEEP + BB)   // 4160 rows through the autoencoder (4160 = 65*64)

// ---------------- K1: cls attention scores (f64 accumulate for exact ranking) ---
__global__ __launch_bounds__(256) void k_scores(const float* __restrict__ cls,
                                                const float* __restrict__ fm,
                                                float* __restrict__ scores)
{
  int gw = (blockIdx.x * blockDim.x + threadIdx.x) >> 6;   // one wave per (b,s)
  int lane = threadIdx.x & 63;
  if (gw >= BB * SS) return;
  int b = gw / SS, s = gw - b * SS;
  const float4* frow = (const float4*)(fm + ((size_t)b * SS + s) * DD);
  const float4* crow = (const float4*)(cls + (size_t)b * DD);
  double acc = 0.0;
#pragma unroll
  for (int j = 0; j < 3; ++j) {
    float4 f = frow[lane + 64 * j];
    float4 c = crow[lane + 64 * j];
    acc += (double)f.x * c.x + (double)f.y * c.y + (double)f.z * c.z + (double)f.w * c.w;
  }
#pragma unroll
  for (int off = 32; off > 0; off >>= 1) acc += __shfl_down(acc, off, 64);
  if (lane == 0) scores[(size_t)b * SS + s] = (float)acc;
}

// ---------------- K2a: top-63 selection, sorted desc, ties -> lowest index -----
__global__ __launch_bounds__(64) void k_topk(const float* __restrict__ scores,
                                             int* __restrict__ idxout)
{
  int b = blockIdx.x, lane = threadIdx.x;
  unsigned long long key[9];
#pragma unroll
  for (int j = 0; j < 9; ++j) {
    int idx = lane + 64 * j;                       // covers 0..575
    unsigned int u = __float_as_uint(scores[(size_t)b * SS + idx]);
    u = (u & 0x80000000u) ? ~u : (u | 0x80000000u);   // order-preserving map
    key[j] = ((unsigned long long)u << 32) |
             (unsigned long long)(0xFFFFFFFFu - (unsigned)idx);  // ties: lower idx wins
  }
  for (int k = 0; k < KTOP; ++k) {
    unsigned long long best = key[0];
#pragma unroll
    for (int j = 1; j < 9; ++j) best = key[j] > best ? key[j] : best;
#pragma unroll
    for (int off = 32; off > 0; off >>= 1) {
      unsigned long long o = __shfl_xor(best, off, 64);
      best = o > best ? o : best;
    }
    int idx = (int)(0xFFFFFFFFu - (unsigned int)best);
    if (lane == 0) idxout[b * KEEP + k] = idx;
    if ((idx & 63) == lane) {                       // remove winner
      int wj = idx >> 6;
#pragma unroll
      for (int j = 0; j < 9; ++j) if (j == wj) key[j] = 0ull;
    }
  }
}

// ---------------- K2b: masked softmax weights + pooled extra token -------------
// grid (64 batches, 6 d-chunks) x 128 threads
__global__ __launch_bounds__(128) void k_extra(const float* __restrict__ scores,
                                               const int* __restrict__ idxin,
                                               const float* __restrict__ fm,
                                               float* __restrict__ extra)
{
  __shared__ float w[SS];
  __shared__ unsigned char flag[SS];
  __shared__ float redm[2], redz[2];
  int b = blockIdx.x, tid = threadIdx.x;
  int d = blockIdx.y * 128 + tid;
  for (int i = tid; i < SS; i += 128) { flag[i] = 0; w[i] = scores[(size_t)b * SS + i]; }
  __syncthreads();
  if (tid < KTOP) flag[idxin[b * KEEP + tid]] = 1;
  __syncthreads();
  // max over unselected (selected logits are score-10000 -> never the max)
  float m = -1e30f;
  for (int i = tid; i < SS; i += 128) if (!flag[i]) m = fmaxf(m, w[i]);
#pragma unroll
  for (int off = 32; off; off >>= 1) m = fmaxf(m, __shfl_xor(m, off, 64));
  if ((tid & 63) == 0) redm[tid >> 6] = m;
  __syncthreads();
  m = fmaxf(redm[0], redm[1]);
  // e_s (selected -> exactly 0, matching f32 exp(-1e4) underflow in the reference)
  float zp = 0.f;
  for (int i = tid; i < SS; i += 128) {
    float e = flag[i] ? 0.f : expf(w[i] - m);
    w[i] = e; zp += e;
  }
#pragma unroll
  for (int off = 32; off; off >>= 1) zp += __shfl_xor(zp, off, 64);
  if ((tid & 63) == 0) redz[tid >> 6] = zp;
  __syncthreads();                                  // also covers w[] writes above
  float Z = redz[0] + redz[1];
  float a0 = 0.f, a1 = 0.f, a2 = 0.f, a3 = 0.f;
  const float* fcol = fm + (size_t)b * SS * DD + d;
#pragma unroll 4
  for (int s = 0; s < SS; s += 4) {
    a0 = fmaf(w[s + 0], fcol[(size_t)(s + 0) * DD], a0);
    a1 = fmaf(w[s + 1], fcol[(size_t)(s + 1) * DD], a1);
    a2 = fmaf(w[s + 2], fcol[(size_t)(s + 2) * DD], a2);
    a3 = fmaf(w[s + 3], fcol[(size_t)(s + 3) * DD], a3);
  }
  extra[(size_t)b * DD + d] = ((a0 + a1) + (a2 + a3)) / Z;
}

// ---------------- K3: partial[kc] = X(rows) @ W1[kc-chunk]  --------------------
// Block = 64 rows x 128 cols, K-chunk 128. 256 threads, per-thread 8x4 register
// tile. X tile + W tile in LDS (101.9 KB -> 1 block/CU, 4 waves). Inner loop:
// per 4 K, 12 ds_read_b128 feed 128 FMAs -> VALU-bound. CPB = K-chunks looped
// per block (1 = partial path, 6 = single-pass fallback when ws is small).
template<int CPB>
__global__ __launch_bounds__(256) void k_ae1(const float* __restrict__ fm,
                                             const float* __restrict__ cls,
                                             const float* __restrict__ extra,
                                             const int* __restrict__ idxin,
                                             const float* __restrict__ W1,
                                             float* __restrict__ partial)
{
  __shared__ float Xs[64][132];        // 33.8 KB (132 words = 16B-aligned rows)
  __shared__ float Ws[128][132];       // 67.6 KB
  __shared__ const float* rowptr[64];
  int g = blockIdx.x;                  // row group: rows g*64 .. +63
  int tid = threadIdx.x;

  if (tid < 64) {
    const float* p;
    if (g < BB) {                      // batch g's KEEP rows
      p = (tid < KTOP) ? fm + ((size_t)g * SS + idxin[g * KEEP + tid]) * DD
                       : extra + (size_t)g * DD;
    } else {                           // cls rows 4096..4159
      p = cls + (size_t)tid * DD;
    }
    rowptr[tid] = p;
  }

  int ty = tid >> 5, tx = tid & 31;
  int r0 = ty * 8, c0 = tx * 4;
  float acc[8][4] = {};

  for (int cc = 0; cc < CPB; ++cc) {
    int kb = (blockIdx.y * CPB + cc) * 128;
    __syncthreads();                   // rowptr ready / previous tile consumed
#pragma unroll
    for (int i = 0; i < 8; ++i) {      // X tile: 2048 float4
      int f4 = tid + 256 * i;
      int r = f4 >> 5, k4 = f4 & 31;
      float4 v = *(const float4*)(rowptr[r] + kb + k4 * 4);
      *(float4*)&Xs[r][k4 * 4] = v;
    }
#pragma unroll
    for (int i = 0; i < 16; ++i) {     // W1 chunk: 4096 float4, coalesced
      int f4 = tid + 256 * i;
      int wr = f4 >> 5, c4 = f4 & 31;
      float4 v = *(const float4*)(W1 + (size_t)(kb + wr) * HH + c4 * 4);
      *(float4*)&Ws[wr][c4 * 4] = v;
    }
    __syncthreads();
#pragma unroll 4
    for (int q = 0; q < 32; ++q) {
      float4 xv[8], wv[4];
#pragma unroll
      for (int i = 0; i < 8; ++i) xv[i] = *(const float4*)&Xs[r0 + i][q * 4];
#pragma unroll
      for (int j = 0; j < 4; ++j) wv[j] = *(const float4*)&Ws[q * 4 + j][c0];
#pragma unroll
      for (int i = 0; i < 8; ++i) {
        float x;
        x = xv[i].x;
        acc[i][0] = fmaf(x, wv[0].x, acc[i][0]); acc[i][1] = fmaf(x, wv[0].y, acc[i][1]);
        acc[i][2] = fmaf(x, wv[0].z, acc[i][2]); acc[i][3] = fmaf(x, wv[0].w, acc[i][3]);
        x = xv[i].y;
        acc[i][0] = fmaf(x, wv[1].x, acc[i][0]); acc[i][1] = fmaf(x, wv[1].y, acc[i][1]);
        acc[i][2] = fmaf(x, wv[1].z, acc[i][2]); acc[i][3] = fmaf(x, wv[1].w, acc[i][3]);
        x = xv[i].z;
        acc[i][0] = fmaf(x, wv[2].x, acc[i][0]); acc[i][1] = fmaf(x, wv[2].y, acc[i][1]);
        acc[i][2] = fmaf(x, wv[2].z, acc[i][2]); acc[i][3] = fmaf(x, wv[2].w, acc[i][3]);
        x = xv[i].w;
        acc[i][0] = fmaf(x, wv[3].x, acc[i][0]); acc[i][1] = fmaf(x, wv[3].y, acc[i][1]);
        acc[i][2] = fmaf(x, wv[3].z, acc[i][2]); acc[i][3] = fmaf(x, wv[3].w, acc[i][3]);
      }
    }
  }
  float* P = partial + (size_t)blockIdx.y * ((size_t)NROW * HH);
#pragma unroll
  for (int i = 0; i < 8; ++i) {
    float4 v = make_float4(acc[i][0], acc[i][1], acc[i][2], acc[i][3]);
    *(float4*)&P[(size_t)(g * 64 + r0 + i) * HH + c0] = v;
  }
}

// ---------------- K4: out = tanh(sum(partial)+b1) @ W2 + b2 --------------------
// Same block structure; H tile built during staging (NP-way reduce + bias +
// tanh), W2 128x128 column slice staged, 32 outputs/thread, K=128.
template<int NP>
__global__ __launch_bounds__(256) void k_ae2(const float* __restrict__ partial,
                                             const float* __restrict__ b1,
                                             const float* __restrict__ W2,
                                             const float* __restrict__ b2,
                                             float* __restrict__ out)
{
  __shared__ float Hs[64][132];
  __shared__ float Ws[128][132];
  int g = blockIdx.x;                  // row group
  int nb = blockIdx.y;                 // column block: cols nb*128 .. +127
  int tid = threadIdx.x;

#pragma unroll
  for (int i = 0; i < 8; ++i) {        // H tile: reduce partials + bias + tanh
    int f4 = tid + 256 * i;
    int r = f4 >> 5, c4 = f4 & 31;
    size_t off = (size_t)(g * 64 + r) * HH + c4 * 4;
    float4 s = *(const float4*)&partial[off];
#pragma unroll
    for (int p = 1; p < NP; ++p) {
      float4 t = *(const float4*)&partial[(size_t)p * NROW * HH + off];
      s.x += t.x; s.y += t.y; s.z += t.z; s.w += t.w;
    }
    float4 bv = *(const float4*)&b1[c4 * 4];
    s.x = tanhf(s.x + bv.x); s.y = tanhf(s.y + bv.y);
    s.z = tanhf(s.z + bv.z); s.w = tanhf(s.w + bv.w);
    *(float4*)&Hs[r][c4 * 4] = s;
  }
#pragma unroll
  for (int i = 0; i < 16; ++i) {       // W2 column slice, coalesced 512B rows
    int f4 = tid + 256 * i;
    int wr = f4 >> 5, c4 = f4 & 31;
    float4 v = *(const float4*)(W2 + (size_t)wr * DD + nb * 128 + c4 * 4);
    *(float4*)&Ws[wr][c4 * 4] = v;
  }
  __syncthreads();

  int ty = tid >> 5, tx = tid & 31;
  int r0 = ty * 8, c0 = tx * 4;
  float acc[8][4] = {};
#pragma unroll 4
  for (int q = 0; q < 32; ++q) {
    float4 xv[8], wv[4];
#pragma unroll
    for (int i = 0; i < 8; ++i) xv[i] = *(const float4*)&Hs[r0 + i][q * 4];
#pragma unroll
    for (int j = 0; j < 4; ++j) wv[j] = *(const float4*)&Ws[q * 4 + j][c0];
#pragma unroll
    for (int i = 0; i < 8; ++i) {
      float x;
      x = xv[i].x;
      acc[i][0] = fmaf(x, wv[0].x, acc[i][0]); acc[i][1] = fmaf(x, wv[0].y, acc[i][1]);
      acc[i][2] = fmaf(x, wv[0].z, acc[i][2]); acc[i][3] = fmaf(x, wv[0].w, acc[i][3]);
      x = xv[i].y;
      acc[i][0] = fmaf(x, wv[1].x, acc[i][0]); acc[i][1] = fmaf(x, wv[1].y, acc[i][1]);
      acc[i][2] = fmaf(x, wv[1].z, acc[i][2]); acc[i][3] = fmaf(x, wv[1].w, acc[i][3]);
      x = xv[i].z;
      acc[i][0] = fmaf(x, wv[2].x, acc[i][0]); acc[i][1] = fmaf(x, wv[2].y, acc[i][1]);
      acc[i][2] = fmaf(x, wv[2].z, acc[i][2]); acc[i][3] = fmaf(x, wv[2].w, acc[i][3]);
      x = xv[i].w;
      acc[i][0] = fmaf(x, wv[3].x, acc[i][0]); acc[i][1] = fmaf(x, wv[3].y, acc[i][1]);
      acc[i][2] = fmaf(x, wv[3].z, acc[i][2]); acc[i][3] = fmaf(x, wv[3].w, acc[i][3]);
    }
  }
  float4 bv = *(const float4*)&b2[nb * 128 + c0];
#pragma unroll
  for (int i = 0; i < 8; ++i) {
    float4 y = make_float4(acc[i][0] + bv.x, acc[i][1] + bv.y,
                           acc[i][2] + bv.z, acc[i][3] + bv.w);
    *(float4*)&out[(size_t)(g * 64 + r0 + i) * DD + nb * 128 + c0] = y;
  }
}

extern "C" void kernel_launch(void* const* d_in, const int* in_sizes, int n_in,
                              void* d_out, int out_size, void* d_ws, size_t ws_size,
                              hipStream_t stream)
{
  const float* cls = (const float*)d_in[0];
  const float* fm  = (const float*)d_in[1];
  const float* W1  = (const float*)d_in[2];
  const float* b1  = (const float*)d_in[3];
  const float* W2  = (const float*)d_in[4];
  const float* b2  = (const float*)d_in[5];
  float* out = (float*)d_out;

  char* ws = (char*)d_ws;
  float* scores  = (float*)ws;                          // 147456 B
  int*   idx     = (int*)(ws + 147456);                 //  16384 B
  float* extra   = (float*)(ws + 147456 + 16384);       // 196608 B
  float* partial = (float*)(ws + 360448);               // NP * 4160*128*4 B

  hipLaunchKernelGGL(k_scores, dim3((BB * SS) / 4), dim3(256), 0, stream, cls, fm, scores);
  hipLaunchKernelGGL(k_topk,   dim3(BB),            dim3(64),  0, stream, scores, idx);
  hipLaunchKernelGGL(k_extra,  dim3(BB, 6),         dim3(128), 0, stream, scores, idx, fm, extra);

  const size_t PSLICE = (size_t)NROW * HH * 4;          // 2129920 B
  if (ws_size >= 360448 + 6 * PSLICE) {
    hipLaunchKernelGGL(k_ae1<1>, dim3(65, 6), dim3(256), 0, stream,
                       fm, cls, extra, idx, W1, partial);
    hipLaunchKernelGGL(k_ae2<6>, dim3(65, 6), dim3(256), 0, stream,
                       partial, b1, W2, b2, out);
  } else {                                              // small-ws fallback
    hipLaunchKernelGGL(k_ae1<6>, dim3(65, 1), dim3(256), 0, stream,
                       fm, cls, extra, idx, W1, partial);
    hipLaunchKernelGGL(k_ae2<1>, dim3(65, 6), dim3(256), 0, stream,
                       partial, b1, W2, b2, out);
  }
}

// Round 5
// 122.295 us; speedup vs baseline: 1.7702x; 1.0722x over previous
//
#include <hip/hip_runtime.h>
#include <math.h>

#define BB   64
#define SS   576
#define DD   768
#define KTOP 63
#define KEEP 64
#define HH   128
#define NROW (BB*KEEP + BB)   // 4160 = 65*64 rows through the autoencoder

// ---------------- K1: cls attention scores (f64 accumulate for exact ranking) ---
__global__ __launch_bounds__(256) void k_scores(const float* __restrict__ cls,
                                                const float* __restrict__ fm,
                                                float* __restrict__ scores)
{
  int gw = (blockIdx.x * blockDim.x + threadIdx.x) >> 6;   // one wave per (b,s)
  int lane = threadIdx.x & 63;
  if (gw >= BB * SS) return;
  int b = gw / SS, s = gw - b * SS;
  const float4* frow = (const float4*)(fm + ((size_t)b * SS + s) * DD);
  const float4* crow = (const float4*)(cls + (size_t)b * DD);
  double acc = 0.0;
#pragma unroll
  for (int j = 0; j < 3; ++j) {
    float4 f = frow[lane + 64 * j];
    float4 c = crow[lane + 64 * j];
    acc += (double)f.x * c.x + (double)f.y * c.y + (double)f.z * c.z + (double)f.w * c.w;
  }
#pragma unroll
  for (int off = 32; off > 0; off >>= 1) acc += __shfl_down(acc, off, 64);
  if (lane == 0) scores[(size_t)b * SS + s] = (float)acc;
}

// ---------------- K2a: top-63 selection, sorted desc, ties -> lowest index -----
__global__ __launch_bounds__(64) void k_topk(const float* __restrict__ scores,
                                             int* __restrict__ idxout)
{
  int b = blockIdx.x, lane = threadIdx.x;
  unsigned long long key[9];
#pragma unroll
  for (int j = 0; j < 9; ++j) {
    int idx = lane + 64 * j;                       // covers 0..575
    unsigned int u = __float_as_uint(scores[(size_t)b * SS + idx]);
    u = (u & 0x80000000u) ? ~u : (u | 0x80000000u);   // order-preserving map
    key[j] = ((unsigned long long)u << 32) |
             (unsigned long long)(0xFFFFFFFFu - (unsigned)idx);  // ties: lower idx wins
  }
  for (int k = 0; k < KTOP; ++k) {
    unsigned long long best = key[0];
#pragma unroll
    for (int j = 1; j < 9; ++j) best = key[j] > best ? key[j] : best;
#pragma unroll
    for (int off = 32; off > 0; off >>= 1) {
      unsigned long long o = __shfl_xor(best, off, 64);
      best = o > best ? o : best;
    }
    int idx = (int)(0xFFFFFFFFu - (unsigned int)best);
    if (lane == 0) idxout[b * KEEP + k] = idx;
    if ((idx & 63) == lane) {                       // remove winner
      int wj = idx >> 6;
#pragma unroll
      for (int j = 0; j < 9; ++j) if (j == wj) key[j] = 0ull;
    }
  }
}

// ---------------- K2b: masked softmax weights + pooled extra token -------------
// grid (64 batches, 6 d-chunks of 128) x 256 threads.
// Phase B: 8 s-rows in flight (sg = tid>>5), float4 loads (512B/row segment).
__global__ __launch_bounds__(256) void k_extra(const float* __restrict__ scores,
                                               const int* __restrict__ idxin,
                                               const float* __restrict__ fm,
                                               float* __restrict__ extra)
{
  __shared__ float w[SS];
  __shared__ unsigned char flag[SS];
  __shared__ float redm[4], redz[4];
  __shared__ float4 red[8][32];
  int b = blockIdx.x, tid = threadIdx.x;
  for (int i = tid; i < SS; i += 256) { flag[i] = 0; w[i] = scores[(size_t)b * SS + i]; }
  __syncthreads();
  if (tid < KTOP) flag[idxin[b * KEEP + tid]] = 1;
  __syncthreads();
  // max over unselected (selected logits are score-10000 -> never the max)
  float m = -1e30f;
  for (int i = tid; i < SS; i += 256) if (!flag[i]) m = fmaxf(m, w[i]);
#pragma unroll
  for (int off = 32; off; off >>= 1) m = fmaxf(m, __shfl_xor(m, off, 64));
  if ((tid & 63) == 0) redm[tid >> 6] = m;
  __syncthreads();
  m = fmaxf(fmaxf(redm[0], redm[1]), fmaxf(redm[2], redm[3]));
  // e_s (selected -> exactly 0, matching f32 exp(-1e4) underflow in reference)
  float zp = 0.f;
  for (int i = tid; i < SS; i += 256) {
    float e = flag[i] ? 0.f : expf(w[i] - m);
    w[i] = e; zp += e;
  }
#pragma unroll
  for (int off = 32; off; off >>= 1) zp += __shfl_xor(zp, off, 64);
  if ((tid & 63) == 0) redz[tid >> 6] = zp;
  __syncthreads();                                  // covers w[] writes too
  float Z = (redz[0] + redz[1]) + (redz[2] + redz[3]);

  int lane = tid & 31, sg = tid >> 5;
  int d4 = blockIdx.y * 128 + lane * 4;             // this thread's float4 column
  const float* fbase = fm + (size_t)b * SS * DD + d4;
  float4 acc = make_float4(0.f, 0.f, 0.f, 0.f);
  for (int s = sg; s < SS; s += 8) {                // 72 iters, 8 rows in flight
    float ws_ = w[s];                               // LDS broadcast
    float4 v = *(const float4*)(fbase + (size_t)s * DD);
    acc.x = fmaf(ws_, v.x, acc.x); acc.y = fmaf(ws_, v.y, acc.y);
    acc.z = fmaf(ws_, v.z, acc.z); acc.w = fmaf(ws_, v.w, acc.w);
  }
  red[sg][lane] = acc;
  __syncthreads();
  if (sg == 0) {
    float4 s0 = red[0][lane];
#pragma unroll
    for (int p = 1; p < 8; ++p) {
      float4 t = red[p][lane];
      s0.x += t.x; s0.y += t.y; s0.z += t.z; s0.w += t.w;
    }
    float4 o = make_float4(s0.x / Z, s0.y / Z, s0.z / Z, s0.w / Z);
    *(float4*)(extra + (size_t)b * DD + d4) = o;
  }
}

// ---------------- K3: partial[y] = X(rows) @ W1[K-chunk y] ---------------------
// Block = 64 rows x 128 cols, K-chunk 64. LDS 51.7 KB -> 3 blocks/CU (12 waves).
// grid (65, 12/CPB). Per-thread 8x4 register tile; per 4-K step 12 ds_read_b128
// (broadcast-heavy) feed 128 FMAs.
template<int CPB>
__global__ __launch_bounds__(256, 3) void k_ae1(const float* __restrict__ fm,
                                                const float* __restrict__ cls,
                                                const float* __restrict__ extra,
                                                const int* __restrict__ idxin,
                                                const float* __restrict__ W1,
                                                float* __restrict__ partial)
{
  __shared__ float Xs[64][68];         // 17.0 KB
  __shared__ float Ws[64][132];        // 33.8 KB
  __shared__ const float* rowptr[64];
  int g = blockIdx.x;                  // row group: rows g*64 .. +63
  int tid = threadIdx.x;

  if (tid < 64) {
    const float* p;
    if (g < BB) {
      p = (tid < KTOP) ? fm + ((size_t)g * SS + idxin[g * KEEP + tid]) * DD
                       : extra + (size_t)g * DD;
    } else {
      p = cls + (size_t)tid * DD;
    }
    rowptr[tid] = p;
  }

  int ty = tid >> 5, tx = tid & 31;
  int r0 = ty * 8, c0 = tx * 4;
  float acc[8][4] = {};

  for (int cc = 0; cc < CPB; ++cc) {
    int kb = (blockIdx.y * CPB + cc) * 64;
    __syncthreads();                   // rowptr ready / previous tile consumed
#pragma unroll
    for (int i = 0; i < 4; ++i) {      // X tile: 64 rows x 16 float4
      int f4 = tid + 256 * i;
      int r = f4 >> 4, k4 = f4 & 15;
      *(float4*)&Xs[r][k4 * 4] = *(const float4*)(rowptr[r] + kb + k4 * 4);
    }
#pragma unroll
    for (int i = 0; i < 8; ++i) {      // W1 chunk: 64 rows x 32 float4
      int f4 = tid + 256 * i;
      int wr = f4 >> 5, c4 = f4 & 31;
      *(float4*)&Ws[wr][c4 * 4] =
          *(const float4*)(W1 + (size_t)(kb + wr) * HH + c4 * 4);
    }
    __syncthreads();
#pragma unroll
    for (int q = 0; q < 16; ++q) {     // 64 K per chunk
      float4 xv[8], wv[4];
#pragma unroll
      for (int i = 0; i < 8; ++i) xv[i] = *(const float4*)&Xs[r0 + i][q * 4];
#pragma unroll
      for (int j = 0; j < 4; ++j) wv[j] = *(const float4*)&Ws[q * 4 + j][c0];
#pragma unroll
      for (int i = 0; i < 8; ++i) {
        float x;
        x = xv[i].x;
        acc[i][0] = fmaf(x, wv[0].x, acc[i][0]); acc[i][1] = fmaf(x, wv[0].y, acc[i][1]);
        acc[i][2] = fmaf(x, wv[0].z, acc[i][2]); acc[i][3] = fmaf(x, wv[0].w, acc[i][3]);
        x = xv[i].y;
        acc[i][0] = fmaf(x, wv[1].x, acc[i][0]); acc[i][1] = fmaf(x, wv[1].y, acc[i][1]);
        acc[i][2] = fmaf(x, wv[1].z, acc[i][2]); acc[i][3] = fmaf(x, wv[1].w, acc[i][3]);
        x = xv[i].z;
        acc[i][0] = fmaf(x, wv[2].x, acc[i][0]); acc[i][1] = fmaf(x, wv[2].y, acc[i][1]);
        acc[i][2] = fmaf(x, wv[2].z, acc[i][2]); acc[i][3] = fmaf(x, wv[2].w, acc[i][3]);
        x = xv[i].w;
        acc[i][0] = fmaf(x, wv[3].x, acc[i][0]); acc[i][1] = fmaf(x, wv[3].y, acc[i][1]);
        acc[i][2] = fmaf(x, wv[3].z, acc[i][2]); acc[i][3] = fmaf(x, wv[3].w, acc[i][3]);
      }
    }
  }
  float* P = partial + (size_t)blockIdx.y * ((size_t)NROW * HH);
#pragma unroll
  for (int i = 0; i < 8; ++i) {
    float4 v = make_float4(acc[i][0], acc[i][1], acc[i][2], acc[i][3]);
    *(float4*)&P[(size_t)(g * 64 + r0 + i) * HH + c0] = v;
  }
}

// ---------------- K3b: H = tanh(sum(partials) + b1) ----------------------------
template<int NP>
__global__ __launch_bounds__(256) void k_hred(const float* __restrict__ partial,
                                              const float* __restrict__ b1,
                                              float* __restrict__ H)
{
  int i4 = blockIdx.x * 256 + threadIdx.x;          // float4 index, 133120 total
  const float4* P = (const float4*)partial;
  float4 s = P[i4];
#pragma unroll
  for (int p = 1; p < NP; ++p) {
    float4 t = P[(size_t)p * (NROW * HH / 4) + i4];
    s.x += t.x; s.y += t.y; s.z += t.z; s.w += t.w;
  }
  float4 bv = ((const float4*)b1)[i4 & 31];         // HH/4 = 32 float4 per row
  s.x = tanhf(s.x + bv.x); s.y = tanhf(s.y + bv.y);
  s.z = tanhf(s.z + bv.z); s.w = tanhf(s.w + bv.w);
  ((float4*)H)[i4] = s;
}

// ---------------- K4: out = H @ W2 + b2 ----------------------------------------
// Block = 64 rows x 64 cols, K=128. LDS 68.6 KB -> 2 blocks/CU. grid (65, 12).
// Per-thread 4x4 tile; per 4-K step 8 ds_read_b128 feed 64 FMAs.
__global__ __launch_bounds__(256, 2) void k_ae2(const float* __restrict__ H,
                                                const float* __restrict__ W2,
                                                const float* __restrict__ b2,
                                                float* __restrict__ out)
{
  __shared__ float Hs[64][132];        // 33.8 KB
  __shared__ float Ws[128][68];        // 34.8 KB
  int g = blockIdx.x;
  int cb = blockIdx.y;                 // column chunk: cols cb*64 .. +63
  int tid = threadIdx.x;

#pragma unroll
  for (int i = 0; i < 8; ++i) {        // H tile: 64 rows x 32 float4
    int f4 = tid + 256 * i;
    int r = f4 >> 5, c4 = f4 & 31;
    *(float4*)&Hs[r][c4 * 4] = *(const float4*)(H + (size_t)(g * 64 + r) * HH + c4 * 4);
  }
#pragma unroll
  for (int i = 0; i < 8; ++i) {        // W2 slice: 128 rows x 16 float4
    int f4 = tid + 256 * i;
    int wr = f4 >> 4, c4 = f4 & 15;
    *(float4*)&Ws[wr][c4 * 4] =
        *(const float4*)(W2 + (size_t)wr * DD + cb * 64 + c4 * 4);
  }
  __syncthreads();

  int ty = tid >> 4, tx = tid & 15;
  int r0 = ty * 4, c0 = tx * 4;
  float acc[4][4] = {};
#pragma unroll 4
  for (int q = 0; q < 32; ++q) {       // K = 128
    float4 xv[4], wv[4];
#pragma unroll
    for (int i = 0; i < 4; ++i) xv[i] = *(const float4*)&Hs[r0 + i][q * 4];
#pragma unroll
    for (int j = 0; j < 4; ++j) wv[j] = *(const float4*)&Ws[q * 4 + j][c0];
#pragma unroll
    for (int i = 0; i < 4; ++i) {
      float x;
      x = xv[i].x;
      acc[i][0] = fmaf(x, wv[0].x, acc[i][0]); acc[i][1] = fmaf(x, wv[0].y, acc[i][1]);
      acc[i][2] = fmaf(x, wv[0].z, acc[i][2]); acc[i][3] = fmaf(x, wv[0].w, acc[i][3]);
      x = xv[i].y;
      acc[i][0] = fmaf(x, wv[1].x, acc[i][0]); acc[i][1] = fmaf(x, wv[1].y, acc[i][1]);
      acc[i][2] = fmaf(x, wv[1].z, acc[i][2]); acc[i][3] = fmaf(x, wv[1].w, acc[i][3]);
      x = xv[i].z;
      acc[i][0] = fmaf(x, wv[2].x, acc[i][0]); acc[i][1] = fmaf(x, wv[2].y, acc[i][1]);
      acc[i][2] = fmaf(x, wv[2].z, acc[i][2]); acc[i][3] = fmaf(x, wv[2].w, acc[i][3]);
      x = xv[i].w;
      acc[i][0] = fmaf(x, wv[3].x, acc[i][0]); acc[i][1] = fmaf(x, wv[3].y, acc[i][1]);
      acc[i][2] = fmaf(x, wv[3].z, acc[i][2]); acc[i][3] = fmaf(x, wv[3].w, acc[i][3]);
    }
  }
  float4 bv = *(const float4*)&b2[cb * 64 + c0];
#pragma unroll
  for (int i = 0; i < 4; ++i) {
    float4 y = make_float4(acc[i][0] + bv.x, acc[i][1] + bv.y,
                           acc[i][2] + bv.z, acc[i][3] + bv.w);
    *(float4*)&out[(size_t)(g * 64 + r0 + i) * DD + cb * 64 + c0] = y;
  }
}

extern "C" void kernel_launch(void* const* d_in, const int* in_sizes, int n_in,
                              void* d_out, int out_size, void* d_ws, size_t ws_size,
                              hipStream_t stream)
{
  const float* cls = (const float*)d_in[0];
  const float* fm  = (const float*)d_in[1];
  const float* W1  = (const float*)d_in[2];
  const float* b1  = (const float*)d_in[3];
  const float* W2  = (const float*)d_in[4];
  const float* b2  = (const float*)d_in[5];
  float* out = (float*)d_out;

  char* ws = (char*)d_ws;
  float* scores  = (float*)ws;                          // 147456 B
  int*   idx     = (int*)(ws + 147456);                 //  16384 B
  float* extra   = (float*)(ws + 147456 + 16384);       // 196608 B
  float* partial = (float*)(ws + 360448);               // NP slices of 2129920 B
  const size_t PSLICE = (size_t)NROW * HH * 4;          // 2129920 B

  hipLaunchKernelGGL(k_scores, dim3((BB * SS) / 4), dim3(256), 0, stream, cls, fm, scores);
  hipLaunchKernelGGL(k_topk,   dim3(BB),            dim3(64),  0, stream, scores, idx);
  hipLaunchKernelGGL(k_extra,  dim3(BB, 6),         dim3(256), 0, stream, scores, idx, fm, extra);

  if (ws_size >= 360448 + 13 * PSLICE) {                // 12 partials + H
    float* H = (float*)(ws + 360448 + 12 * PSLICE);
    hipLaunchKernelGGL(k_ae1<1>,  dim3(65, 12),      dim3(256), 0, stream,
                       fm, cls, extra, idx, W1, partial);
    hipLaunchKernelGGL(k_hred<12>, dim3(NROW * HH / 1024), dim3(256), 0, stream,
                       partial, b1, H);
    hipLaunchKernelGGL(k_ae2,     dim3(65, 12),      dim3(256), 0, stream, H, W2, b2, out);
  } else {                                              // small-ws fallback
    float* H = (float*)(ws + 360448 + PSLICE);
    hipLaunchKernelGGL(k_ae1<12>, dim3(65, 1),       dim3(256), 0, stream,
                       fm, cls, extra, idx, W1, partial);
    hipLaunchKernelGGL(k_hred<1>, dim3(NROW * HH / 1024), dim3(256), 0, stream,
                       partial, b1, H);
    hipLaunchKernelGGL(k_ae2,     dim3(65, 12),      dim3(256), 0, stream, H, W2, b2, out);
  }
}

// Round 6
// 99.227 us; speedup vs baseline: 2.1817x; 1.2325x over previous
//
#include <hip/hip_runtime.h>
#include <math.h>

#define BB   64
#define SS   576
#define DD   768
#define KTOP 63
#define KEEP 64
#define HH   128
#define NROW (BB*KEEP + BB)   // 4160 = 65*64 rows through the autoencoder
#define SCH  24               // s-chunk size for k_extra2 (576 = 24*24)

typedef unsigned long long ull;

// ---------------- K1: cls attention scores (f64 accumulate for exact ranking) ---
__global__ __launch_bounds__(256) void k_scores(const float* __restrict__ cls,
                                                const float* __restrict__ fm,
                                                float* __restrict__ scores)
{
  int gw = (blockIdx.x * blockDim.x + threadIdx.x) >> 6;   // one wave per (b,s)
  int lane = threadIdx.x & 63;
  if (gw >= BB * SS) return;
  int b = gw / SS, s = gw - b * SS;
  const float4* frow = (const float4*)(fm + ((size_t)b * SS + s) * DD);
  const float4* crow = (const float4*)(cls + (size_t)b * DD);
  double acc = 0.0;
#pragma unroll
  for (int j = 0; j < 3; ++j) {
    float4 f = frow[lane + 64 * j];
    float4 c = crow[lane + 64 * j];
    acc += (double)f.x * c.x + (double)f.y * c.y + (double)f.z * c.z + (double)f.w * c.w;
  }
#pragma unroll
  for (int off = 32; off > 0; off >>= 1) acc += __shfl_down(acc, off, 64);
  if (lane == 0) scores[(size_t)b * SS + s] = (float)acc;
}

// ---------------- K2: rank-select top-63 + normalized softmax weights ----------
// One 576-thread block per batch. Thread s: rank = #{keys > key_s} (keys unique
// -> rank unique, == position in desc sort with lower-index-first ties, matching
// jax.lax.top_k). rank<63 -> selected. Then masked softmax: w' = e/Z (0 if
// selected; matches f32 exp(-1e4) underflow in the reference).
__global__ __launch_bounds__(576) void k_rank(const float* __restrict__ scores,
                                              int* __restrict__ idxout,
                                              float* __restrict__ wprime)
{
  __shared__ ull keys[SS];
  __shared__ float redm[9], redz[9];
  int b = blockIdx.x, tid = threadIdx.x;          // tid == s (0..575)
  int lane = tid & 63, wid = tid >> 6;            // 9 waves
  float sc = scores[(size_t)b * SS + tid];
  unsigned int u = __float_as_uint(sc);
  u = (u & 0x80000000u) ? ~u : (u | 0x80000000u); // order-preserving map
  ull key = ((ull)u << 32) | (ull)(0xFFFFFFFFu - (unsigned)tid);
  keys[tid] = key;
  __syncthreads();
  int rank = 0;
#pragma unroll 8
  for (int s = 0; s < SS; ++s) rank += (keys[s] > key) ? 1 : 0;   // LDS broadcast
  bool sel = rank < KTOP;
  if (sel) idxout[b * KEEP + rank] = tid;
  // max over unselected (selected logits are sc-10000 -> never the max)
  float m = sel ? -1e30f : sc;
#pragma unroll
  for (int off = 32; off; off >>= 1) m = fmaxf(m, __shfl_xor(m, off, 64));
  if (lane == 0) redm[wid] = m;
  __syncthreads();
  float M = redm[0];
#pragma unroll
  for (int i = 1; i < 9; ++i) M = fmaxf(M, redm[i]);
  float e = sel ? 0.f : expf(sc - M);
  float z = e;
#pragma unroll
  for (int off = 32; off; off >>= 1) z += __shfl_xor(z, off, 64);
  if (lane == 0) redz[wid] = z;
  __syncthreads();
  float Z = redz[0];
#pragma unroll
  for (int i = 1; i < 9; ++i) Z += redz[i];
  wprime[(size_t)b * SS + tid] = e / Z;
}

// ---------------- K2b: partial weighted sums over 24-row chunks ----------------
// grid (64, 24) x 192 thr. Thread owns one float4 column; 24 fully-unrolled
// independent loads in flight -> latency-hiding via MLP (4608 waves).
__global__ __launch_bounds__(192) void k_extra2(const float* __restrict__ wprime,
                                                const float* __restrict__ fm,
                                                float* __restrict__ epart)
{
  int b = blockIdx.x, p = blockIdx.y, tid = threadIdx.x;   // tid = float4 col
  const float* fbase = fm + ((size_t)b * SS + p * SCH) * DD + tid * 4;
  const float* wp = wprime + (size_t)b * SS + p * SCH;
  float4 acc = make_float4(0.f, 0.f, 0.f, 0.f);
#pragma unroll
  for (int r = 0; r < SCH; ++r) {
    float w = wp[r];                                       // uniform -> s_load
    float4 v = *(const float4*)(fbase + (size_t)r * DD);
    acc.x = fmaf(w, v.x, acc.x); acc.y = fmaf(w, v.y, acc.y);
    acc.z = fmaf(w, v.z, acc.z); acc.w = fmaf(w, v.w, acc.w);
  }
  *(float4*)(epart + ((size_t)(b * SCH + p) * DD) + tid * 4) = acc;
}

// ---------------- K2c: reduce 24 partials -> extra token -----------------------
__global__ __launch_bounds__(256) void k_ered(const float* __restrict__ epart,
                                              float* __restrict__ extra)
{
  int i = blockIdx.x * 256 + threadIdx.x;                  // 12288 float4 outputs
  int b = i / (DD / 4), c4 = i - b * (DD / 4);
  const float4* P = (const float4*)epart;
  float4 s = make_float4(0.f, 0.f, 0.f, 0.f);
#pragma unroll
  for (int p = 0; p < SCH; ++p) {
    float4 t = P[(size_t)(b * SCH + p) * (DD / 4) + c4];
    s.x += t.x; s.y += t.y; s.z += t.z; s.w += t.w;
  }
  ((float4*)extra)[i] = s;
}

// ---------------- K3: partial[y] = X(rows) @ W1[K-chunk y] ---------------------
// Block = 64 rows x 128 cols, K-chunk 64. LDS 51.7 KB -> 3 blocks/CU (12 waves).
template<int CPB>
__global__ __launch_bounds__(256, 3) void k_ae1(const float* __restrict__ fm,
                                                const float* __restrict__ cls,
                                                const float* __restrict__ extra,
                                                const int* __restrict__ idxin,
                                                const float* __restrict__ W1,
                                                float* __restrict__ partial)
{
  __shared__ float Xs[64][68];         // 17.0 KB
  __shared__ float Ws[64][132];        // 33.8 KB
  __shared__ const float* rowptr[64];
  int g = blockIdx.x;                  // row group: rows g*64 .. +63
  int tid = threadIdx.x;

  if (tid < 64) {
    const float* p;
    if (g < BB) {
      p = (tid < KTOP) ? fm + ((size_t)g * SS + idxin[g * KEEP + tid]) * DD
                       : extra + (size_t)g * DD;
    } else {
      p = cls + (size_t)tid * DD;
    }
    rowptr[tid] = p;
  }

  int ty = tid >> 5, tx = tid & 31;
  int r0 = ty * 8, c0 = tx * 4;
  float acc[8][4] = {};

  for (int cc = 0; cc < CPB; ++cc) {
    int kb = (blockIdx.y * CPB + cc) * 64;
    __syncthreads();                   // rowptr ready / previous tile consumed
#pragma unroll
    for (int i = 0; i < 4; ++i) {      // X tile: 64 rows x 16 float4
      int f4 = tid + 256 * i;
      int r = f4 >> 4, k4 = f4 & 15;
      *(float4*)&Xs[r][k4 * 4] = *(const float4*)(rowptr[r] + kb + k4 * 4);
    }
#pragma unroll
    for (int i = 0; i < 8; ++i) {      // W1 chunk: 64 rows x 32 float4
      int f4 = tid + 256 * i;
      int wr = f4 >> 5, c4 = f4 & 31;
      *(float4*)&Ws[wr][c4 * 4] =
          *(const float4*)(W1 + (size_t)(kb + wr) * HH + c4 * 4);
    }
    __syncthreads();
#pragma unroll
    for (int q = 0; q < 16; ++q) {     // 64 K per chunk
      float4 xv[8], wv[4];
#pragma unroll
      for (int i = 0; i < 8; ++i) xv[i] = *(const float4*)&Xs[r0 + i][q * 4];
#pragma unroll
      for (int j = 0; j < 4; ++j) wv[j] = *(const float4*)&Ws[q * 4 + j][c0];
#pragma unroll
      for (int i = 0; i < 8; ++i) {
        float x;
        x = xv[i].x;
        acc[i][0] = fmaf(x, wv[0].x, acc[i][0]); acc[i][1] = fmaf(x, wv[0].y, acc[i][1]);
        acc[i][2] = fmaf(x, wv[0].z, acc[i][2]); acc[i][3] = fmaf(x, wv[0].w, acc[i][3]);
        x = xv[i].y;
        acc[i][0] = fmaf(x, wv[1].x, acc[i][0]); acc[i][1] = fmaf(x, wv[1].y, acc[i][1]);
        acc[i][2] = fmaf(x, wv[1].z, acc[i][2]); acc[i][3] = fmaf(x, wv[1].w, acc[i][3]);
        x = xv[i].z;
        acc[i][0] = fmaf(x, wv[2].x, acc[i][0]); acc[i][1] = fmaf(x, wv[2].y, acc[i][1]);
        acc[i][2] = fmaf(x, wv[2].z, acc[i][2]); acc[i][3] = fmaf(x, wv[2].w, acc[i][3]);
        x = xv[i].w;
        acc[i][0] = fmaf(x, wv[3].x, acc[i][0]); acc[i][1] = fmaf(x, wv[3].y, acc[i][1]);
        acc[i][2] = fmaf(x, wv[3].z, acc[i][2]); acc[i][3] = fmaf(x, wv[3].w, acc[i][3]);
      }
    }
  }
  float* P = partial + (size_t)blockIdx.y * ((size_t)NROW * HH);
#pragma unroll
  for (int i = 0; i < 8; ++i) {
    float4 v = make_float4(acc[i][0], acc[i][1], acc[i][2], acc[i][3]);
    *(float4*)&P[(size_t)(g * 64 + r0 + i) * HH + c0] = v;
  }
}

// ---------------- K3b: H = tanh(sum(partials) + b1) ----------------------------
template<int NP>
__global__ __launch_bounds__(256) void k_hred(const float* __restrict__ partial,
                                              const float* __restrict__ b1,
                                              float* __restrict__ H)
{
  int i4 = blockIdx.x * 256 + threadIdx.x;          // float4 index, 133120 total
  const float4* P = (const float4*)partial;
  float4 s = P[i4];
#pragma unroll
  for (int p = 1; p < NP; ++p) {
    float4 t = P[(size_t)p * (NROW * HH / 4) + i4];
    s.x += t.x; s.y += t.y; s.z += t.z; s.w += t.w;
  }
  float4 bv = ((const float4*)b1)[i4 & 31];         // HH/4 = 32 float4 per row
  s.x = tanhf(s.x + bv.x); s.y = tanhf(s.y + bv.y);
  s.z = tanhf(s.z + bv.z); s.w = tanhf(s.w + bv.w);
  ((float4*)H)[i4] = s;
}

// ---------------- K4: out = H @ W2 + b2 ----------------------------------------
// Block = 64 rows x 64 cols, K=128. LDS 68.6 KB -> 2 blocks/CU. grid (65, 12).
__global__ __launch_bounds__(256, 2) void k_ae2(const float* __restrict__ H,
                                                const float* __restrict__ W2,
                                                const float* __restrict__ b2,
                                                float* __restrict__ out)
{
  __shared__ float Hs[64][132];        // 33.8 KB
  __shared__ float Ws[128][68];        // 34.8 KB
  int g = blockIdx.x;
  int cb = blockIdx.y;                 // column chunk: cols cb*64 .. +63
  int tid = threadIdx.x;

#pragma unroll
  for (int i = 0; i < 8; ++i) {        // H tile: 64 rows x 32 float4
    int f4 = tid + 256 * i;
    int r = f4 >> 5, c4 = f4 & 31;
    *(float4*)&Hs[r][c4 * 4] = *(const float4*)(H + (size_t)(g * 64 + r) * HH + c4 * 4);
  }
#pragma unroll
  for (int i = 0; i < 8; ++i) {        // W2 slice: 128 rows x 16 float4
    int f4 = tid + 256 * i;
    int wr = f4 >> 4, c4 = f4 & 15;
    *(float4*)&Ws[wr][c4 * 4] =
        *(const float4*)(W2 + (size_t)wr * DD + cb * 64 + c4 * 4);
  }
  __syncthreads();

  int ty = tid >> 4, tx = tid & 15;
  int r0 = ty * 4, c0 = tx * 4;
  float acc[4][4] = {};
#pragma unroll 4
  for (int q = 0; q < 32; ++q) {       // K = 128
    float4 xv[4], wv[4];
#pragma unroll
    for (int i = 0; i < 4; ++i) xv[i] = *(const float4*)&Hs[r0 + i][q * 4];
#pragma unroll
    for (int j = 0; j < 4; ++j) wv[j] = *(const float4*)&Ws[q * 4 + j][c0];
#pragma unroll
    for (int i = 0; i < 4; ++i) {
      float x;
      x = xv[i].x;
      acc[i][0] = fmaf(x, wv[0].x, acc[i][0]); acc[i][1] = fmaf(x, wv[0].y, acc[i][1]);
      acc[i][2] = fmaf(x, wv[0].z, acc[i][2]); acc[i][3] = fmaf(x, wv[0].w, acc[i][3]);
      x = xv[i].y;
      acc[i][0] = fmaf(x, wv[1].x, acc[i][0]); acc[i][1] = fmaf(x, wv[1].y, acc[i][1]);
      acc[i][2] = fmaf(x, wv[1].z, acc[i][2]); acc[i][3] = fmaf(x, wv[1].w, acc[i][3]);
      x = xv[i].z;
      acc[i][0] = fmaf(x, wv[2].x, acc[i][0]); acc[i][1] = fmaf(x, wv[2].y, acc[i][1]);
      acc[i][2] = fmaf(x, wv[2].z, acc[i][2]); acc[i][3] = fmaf(x, wv[2].w, acc[i][3]);
      x = xv[i].w;
      acc[i][0] = fmaf(x, wv[3].x, acc[i][0]); acc[i][1] = fmaf(x, wv[3].y, acc[i][1]);
      acc[i][2] = fmaf(x, wv[3].z, acc[i][2]); acc[i][3] = fmaf(x, wv[3].w, acc[i][3]);
    }
  }
  float4 bv = *(const float4*)&b2[cb * 64 + c0];
#pragma unroll
  for (int i = 0; i < 4; ++i) {
    float4 y = make_float4(acc[i][0] + bv.x, acc[i][1] + bv.y,
                           acc[i][2] + bv.z, acc[i][3] + bv.w);
    *(float4*)&out[(size_t)(g * 64 + r0 + i) * DD + cb * 64 + c0] = y;
  }
}

extern "C" void kernel_launch(void* const* d_in, const int* in_sizes, int n_in,
                              void* d_out, int out_size, void* d_ws, size_t ws_size,
                              hipStream_t stream)
{
  const float* cls = (const float*)d_in[0];
  const float* fm  = (const float*)d_in[1];
  const float* W1  = (const float*)d_in[2];
  const float* b1  = (const float*)d_in[3];
  const float* W2  = (const float*)d_in[4];
  const float* b2  = (const float*)d_in[5];
  float* out = (float*)d_out;

  char* ws = (char*)d_ws;
  float* scores  = (float*)ws;                          // 147456 B
  int*   idx     = (int*)(ws + 147456);                 //  16384 B
  float* extra   = (float*)(ws + 163840);               // 196608 B
  float* wprime  = (float*)(ws + 360448);               // 147456 B
  float* epart   = (float*)(ws + 507904);               // 64*24*768*4 = 4718592 B
  float* partial = (float*)(ws + 5226496);              // NP slices of 2129920 B
  const size_t PSLICE = (size_t)NROW * HH * 4;          // 2129920 B

  hipLaunchKernelGGL(k_scores, dim3((BB * SS) / 4), dim3(256), 0, stream, cls, fm, scores);
  hipLaunchKernelGGL(k_rank,   dim3(BB),            dim3(576), 0, stream, scores, idx, wprime);
  hipLaunchKernelGGL(k_extra2, dim3(BB, SCH),       dim3(192), 0, stream, wprime, fm, epart);
  hipLaunchKernelGGL(k_ered,   dim3(BB * DD / 1024), dim3(256), 0, stream, epart, extra);

  if (ws_size >= 5226496 + 13 * PSLICE) {               // 12 partials + H
    float* H = (float*)(ws + 5226496 + 12 * PSLICE);
    hipLaunchKernelGGL(k_ae1<1>,  dim3(65, 12),      dim3(256), 0, stream,
                       fm, cls, extra, idx, W1, partial);
    hipLaunchKernelGGL(k_hred<12>, dim3(NROW * HH / 1024), dim3(256), 0, stream,
                       partial, b1, H);
    hipLaunchKernelGGL(k_ae2,     dim3(65, 12),      dim3(256), 0, stream, H, W2, b2, out);
  } else {                                              // small-ws fallback
    float* H = (float*)(ws + 5226496 + PSLICE);
    hipLaunchKernelGGL(k_ae1<12>, dim3(65, 1),       dim3(256), 0, stream,
                       fm, cls, extra, idx, W1, partial);
    hipLaunchKernelGGL(k_hred<1>, dim3(NROW * HH / 1024), dim3(256), 0, stream,
                       partial, b1, H);
    hipLaunchKernelGGL(k_ae2,     dim3(65, 12),      dim3(256), 0, stream, H, W2, b2, out);
  }
}